// Round 6
// baseline (321.914 us; speedup 1.0000x reference)
//
#include <hip/hip_runtime.h>
#include <stdint.h>

// DILATE loss, B=32, L=512, DIM=16, gamma=1e-3, alpha=0.5.
//
// Round-6 structure:
//   kA : D[b][j][i] column-major (unchanged).
//   kFG: one wave per batch.
//     Forward hard-min DP, SKEW-2 wavefront: lane l owns rows 8l+1..8l+8 and
//     processes columns cA=2(T-l), cB=cA+1 at macro-step T (T=0..318).
//     Dir bits as two planes per (lane, col-pair): w0[k]=diag-eq, w1[k]=up-eq,
//     accumulated MSB-first via w=w+w+(cmp) (v_addc codegen). Bit for
//     (col parity p, row r) at position (p?7:15)-r; plane1 at +16.
//     u64 tile = 8 rows x 4 cols: lo u32 = col-pair 2q, hi = 2q+1.
//     Backward = serial path trace over LDS tiles, 3-neighbor speculation.
//   kC : combine -> scalar loss.
//
// Decode priority (matches softmin argmin tie order): diag > up > left.

#define N 512
#define NB 32
#define BIGF 1e10f

typedef unsigned int u32;
typedef float f32x4 __attribute__((ext_vector_type(4)));

// ---------------- kA: pairwise squared distances, column-major -------------
__global__ __launch_bounds__(512) void kA(const float* __restrict__ inp,
                                          const float* __restrict__ tgt,
                                          float* __restrict__ Dg) {
    const int b = blockIdx.y;
    const int jc = blockIdx.x;         // group of 4 columns
    const int tid = (int)threadIdx.x;  // row index i0 in [0,512)
    __shared__ float xs[4][16];        // x[j] = inp[b,j]-inp[b,0]
    if (tid < 64) {
        int c = tid >> 4, d = tid & 15;
        int j = jc * 4 + c;
        xs[c][d] = inp[(((size_t)b * N + j) << 4) + d] -
                   inp[(((size_t)b * N) << 4) + d];
    }
    __syncthreads();
    const float4* t4 = (const float4*)(tgt + (((size_t)b * N + tid) << 4));
    float4 ta = t4[0], tb = t4[1], tc = t4[2], td = t4[3];
    float* out = Dg + ((size_t)b * N + (size_t)jc * 4) * N + tid;
#pragma unroll
    for (int c = 0; c < 4; ++c) {
        float s = 0.f, e;
        e = ta.x - xs[c][0];  s = fmaf(e, e, s);
        e = ta.y - xs[c][1];  s = fmaf(e, e, s);
        e = ta.z - xs[c][2];  s = fmaf(e, e, s);
        e = ta.w - xs[c][3];  s = fmaf(e, e, s);
        e = tb.x - xs[c][4];  s = fmaf(e, e, s);
        e = tb.y - xs[c][5];  s = fmaf(e, e, s);
        e = tb.z - xs[c][6];  s = fmaf(e, e, s);
        e = tb.w - xs[c][7];  s = fmaf(e, e, s);
        e = tc.x - xs[c][8];  s = fmaf(e, e, s);
        e = tc.y - xs[c][9];  s = fmaf(e, e, s);
        e = tc.z - xs[c][10]; s = fmaf(e, e, s);
        e = tc.w - xs[c][11]; s = fmaf(e, e, s);
        e = td.x - xs[c][12]; s = fmaf(e, e, s);
        e = td.y - xs[c][13]; s = fmaf(e, e, s);
        e = td.z - xs[c][14]; s = fmaf(e, e, s);
        e = td.w - xs[c][15]; s = fmaf(e, e, s);
        out[(size_t)c * N] = s;
    }
}

// ---------------- kFG: forward DP (skew-2) + path trace --------------------
__global__ __launch_bounds__(64) void kFG(const float* __restrict__ Dg,
                                          float* __restrict__ acc) {
    const int b = blockIdx.x;
    const int l = (int)threadIdx.x;
    const float* Db = Dg + (size_t)b * N * N;

    __shared__ uint2 dirW[129 * 64];  // [quad 0..127, 128=dump][lane], u64 tile

    // slot data: columns cA (A0:rows0-3, A1:rows4-7) and cB (B0,B1)
    f32x4 A0[4], A1[4], B0[4], B1[4];
    const float* pS[4];

#define LOADC(s_, Tt)                                                         \
    do {                                                                      \
        int c_ = min(max(2 * ((Tt) - l), 0), 510);                            \
        const float* p_ = Db + ((size_t)c_ << 9) + (l << 3);                  \
        A0[s_] = ((const f32x4*)p_)[0];  A1[s_] = ((const f32x4*)p_)[1];      \
        B0[s_] = ((const f32x4*)(p_ + 512))[0];                               \
        B1[s_] = ((const f32x4*)(p_ + 512))[1];                               \
    } while (0)

#define LOADP(s_)                                                             \
    do {                                                                      \
        A0[s_] = ((const f32x4*)pS[s_])[0];                                   \
        A1[s_] = ((const f32x4*)pS[s_])[1];                                   \
        B0[s_] = ((const f32x4*)(pS[s_] + 512))[0];                           \
        B1[s_] = ((const f32x4*)(pS[s_] + 512))[1];                           \
        pS[s_] += 4096;                                                       \
    } while (0)

    float Rprev[8];
#pragma unroll
    for (int r = 0; r < 8; ++r) Rprev[r] = BIGF;
    float sA = BIGF, sB = BIGF, sBold = BIGF, Rfin = 0.f;
    u32 q0 = 0, q1 = 0;

    LOADC(0, 0); LOADC(1, 1); LOADC(2, 2); LOADC(3, 3);

    // PH: 0=prologue (validity+clamped reload), 1=steady, 2=epilogue
#define MSTEP(T_, s_, PH)                                                     \
    do {                                                                      \
        const int cpair = (T_) - l;                                           \
        const bool valid = (PH == 1) || ((unsigned)cpair < 256u);             \
        float dA0 = (l == 0) ? BIGF : sBold;                                  \
        if (PH == 0) dA0 = (l == 0 && (T_) == 0) ? 0.f : dA0;                 \
        const float upA0 = (l == 0) ? BIGF : sA;                              \
        const float upB0 = (l == 0) ? BIGF : sB;                              \
        float RcA[8], RcB[8];                                                 \
        u32 w0 = 0, w1 = 0;                                                   \
        _Pragma("unroll") for (int r = 0; r < 8; ++r) {                       \
            float up = (r == 0) ? upA0 : RcA[r - 1];                          \
            float dg = (r == 0) ? dA0 : Rprev[r - 1];                         \
            float lf = Rprev[r];                                              \
            float mn = fminf(up, fminf(dg, lf));                              \
            w0 = w0 + w0 + (u32)(mn == dg);                                   \
            w1 = w1 + w1 + (u32)(mn == up);                                   \
            RcA[r] = ((r < 4) ? A0[s_][(r) & 3] : A1[s_][(r) & 3]) + mn;      \
        }                                                                     \
        _Pragma("unroll") for (int r = 0; r < 8; ++r) {                       \
            float up = (r == 0) ? upB0 : RcB[r - 1];                          \
            float dg = (r == 0) ? upA0 : RcA[r - 1];                          \
            float lf = RcA[r];                                                \
            float mn = fminf(up, fminf(dg, lf));                              \
            w0 = w0 + w0 + (u32)(mn == dg);                                   \
            w1 = w1 + w1 + (u32)(mn == up);                                   \
            RcB[r] = ((r < 4) ? B0[s_][(r) & 3] : B1[s_][(r) & 3]) + mn;      \
        }                                                                     \
        if (PH == 1) {                                                        \
            _Pragma("unroll") for (int r = 0; r < 8; ++r) Rprev[r] = RcB[r];  \
        } else {                                                              \
            _Pragma("unroll") for (int r = 0; r < 8; ++r)                     \
                Rprev[r] = valid ? RcB[r] : Rprev[r];                         \
        }                                                                     \
        const u32 w01 = (w1 << 16) | w0;                                      \
        const int h = cpair & 1;                                              \
        q0 = h ? q0 : w01;                                                    \
        q1 = h ? w01 : q1;                                                    \
        const int quad = (PH == 1) ? (cpair >> 1) : (valid ? (cpair >> 1) : 128); \
        dirW[(quad << 6) | l] = make_uint2(q0, q1);                           \
        float exA = RcA[7], exB = RcB[7];                                     \
        if (PH != 1) {                                                        \
            exA = valid ? exA : BIGF;                                         \
            exB = valid ? exB : BIGF;                                         \
        }                                                                     \
        if (PH == 2) { if (cpair == 255) Rfin = RcB[7]; }                     \
        sBold = sB;                                                           \
        sA = __shfl_up(exA, 1);                                               \
        sB = __shfl_up(exB, 1);                                               \
        if (PH == 1) { LOADP(s_); } else { LOADC(s_, (T_) + 4); }             \
    } while (0)

    // prologue: T = 0..63
    for (int T = 0; T < 64; T += 4) {
        MSTEP(T + 0, 0, 0); MSTEP(T + 1, 1, 0);
        MSTEP(T + 2, 2, 0); MSTEP(T + 3, 3, 0);
    }
    // steady: T = 64..251 (all lanes valid; reload targets T+4 <= 255 valid)
#pragma unroll
    for (int s = 0; s < 4; ++s)
        pS[s] = Db + ((size_t)(2 * (68 + s - l)) << 9) + (l << 3);
    for (int T = 64; T < 252; T += 4) {
        MSTEP(T + 0, 0, 1); MSTEP(T + 1, 1, 1);
        MSTEP(T + 2, 2, 1); MSTEP(T + 3, 3, 1);
    }
    // epilogue: T = 252..319 (covers last real step T=318; T=319 all-dump)
    for (int T = 252; T < 320; T += 4) {
        MSTEP(T + 0, 0, 2); MSTEP(T + 1, 1, 2);
        MSTEP(T + 2, 2, 2); MSTEP(T + 3, 3, 2);
    }
#undef MSTEP
#undef LOADC
#undef LOADP

    if (l == 63) acc[b] = Rfin;  // Rp[N,N]: hard-DTW value

    asm volatile("s_waitcnt lgkmcnt(0)" ::: "memory");

    // ================= backward: serial path trace =================
    // All lanes run the identical trace (uniform branches, LDS broadcast).
    {
        int i = N, j = N;  // 1-based
        float tsum = 0.f;
        int L = (N - 1) >> 3, Q = (N - 1) >> 2;  // 63, 127
        uint2 w = dirW[(Q << 6) | L];
        bool done = false;
        for (int g = 0; g < 1100 && !done; ++g) {
            const int Lm = L > 0 ? L - 1 : 0;
            const int Qm = Q > 0 ? Q - 1 : 0;
            uint2 wU = dirW[(Q << 6) | Lm];   // cross row-block, same quad
            uint2 wL = dirW[(Qm << 6) | L];   // same row-block, quad left
            uint2 wD = dirW[(Qm << 6) | Lm];  // both
            while (true) {
                const int row0 = i - 1, col0 = j - 1;
                const u32 v = ((col0 >> 1) & 1) ? w.y : w.x;
                const int s = ((col0 & 1) ? 7 : 15) - (row0 & 7);
                const u32 bd = (v >> s) & 1u;
                const u32 bu = (v >> (s + 16)) & 1u;
                const int di = (int)(bd | bu);
                const int dj = (int)(bd | (bu ^ 1u));  // diag/left move j
                i -= di; j -= dj;
                const int d = i - j;
                tsum += (float)(d * d);
                if ((i | j) == 1) { done = true; break; }  // reached (1,1)
                const int nL = (i - 1) >> 3, nQ = (j - 1) >> 2;
                if ((nL != L) || (nQ != Q)) {
                    w = (nQ != Q) ? ((nL != L) ? wD : wL) : wU;
                    L = nL; Q = nQ;
                    break;  // re-speculate neighbors
                }
            }
        }
        if (l == 0) acc[NB + b] = tsum;
    }
}

// ---------------- kC: combine over batches ---------------------------------
__global__ void kC(const float* __restrict__ acc, float* __restrict__ out) {
    const int l = (int)threadIdx.x;
    float vs = (l < NB) ? acc[l] : 0.f;
    float vt = (l < NB) ? acc[NB + l] : 0.f;
#pragma unroll
    for (int o = 32; o >= 1; o >>= 1) {
        vs += __shfl_down(vs, o);
        vt += __shfl_down(vt, o);
    }
    if (l == 0)
        out[0] = 0.5f * (vs / (float)NB) +
                 0.5f * (vt / ((float)NB * (float)(N * N)));
}

__global__ void kSentinel(float* out) { out[0] = -12345.0f; }

extern "C" void kernel_launch(void* const* d_in, const int* in_sizes, int n_in,
                              void* d_out, int out_size, void* d_ws, size_t ws_size,
                              hipStream_t stream) {
    const float* inp = (const float*)d_in[0];
    const float* tgt = (const float*)d_in[1];
    float* out = (float*)d_out;

    const size_t DSZ = (size_t)NB * N * N * sizeof(float);  // 32 MiB
    const size_t NEEDED = 256 + DSZ;
    if (ws_size < NEEDED) {
        kSentinel<<<1, 1, 0, stream>>>(out);
        return;
    }
    char* ws = (char*)d_ws;
    float* acc = (float*)ws;  // [0..31] shape, [32..63] temporal
    float* Dg = (float*)(ws + 256);

    kA<<<dim3(N / 4, NB), 512, 0, stream>>>(inp, tgt, Dg);
    kFG<<<NB, 64, 0, stream>>>(Dg, acc);
    kC<<<1, 64, 0, stream>>>(acc, out);
}